// Round 2
// baseline (1003.236 us; speedup 1.0000x reference)
//
#include <hip/hip_runtime.h>
#include <stdint.h>

#define D_MODEL 5376
#define D_HID   100
#define NH      10
#define WIN     10
#define BATCH   8
#define TLEN    4096
#define M_TOT   (BATCH*TLEN)      // 32768
#define KITERS  (D_MODEL/32)      // 168
#define BM      64

// workspace layout (bytes)
#define WS_W1P  0                 // 168*8192 = 1376256
#define WS_W2P  1376256           // 4*8192   = 32768
#define WS_QVP  1409024           // 4*2048   = 8192
#define WS_B1P  1417216           // 512
#define WS_B2P  1417728           // 512
#define WS_AV   1418240           // 32768*32*4 = 4194304
#define WS_HMAX 5612544           // 80*4

typedef __attribute__((ext_vector_type(8))) short short8;
typedef __attribute__((ext_vector_type(4))) float f32x4;

__device__ __forceinline__ short f2bf(float f) {
    uint32_t u = __float_as_uint(f);
    u += 0x7fff + ((u >> 16) & 1);   // round-to-nearest-even
    return (short)(u >> 16);
}

// ---------------- prep: pack W1/W2/qv to bf16, K-blocked + swizzled ----------
__global__ void prep_kernel(const float* __restrict__ W1, const float* __restrict__ b1,
                            const float* __restrict__ W2, const float* __restrict__ b2,
                            const float* __restrict__ q,  const float* __restrict__ v,
                            char* __restrict__ ws) {
    int id = blockIdx.x * 256 + threadIdx.x;
    if (id < 86016) {                 // W1p: 168 kb * 128 n * 4 kkb
        int kb = id >> 9;
        int rem = id & 511;
        int n = rem >> 2, kkb = rem & 3;
        short8 o;
        #pragma unroll
        for (int j = 0; j < 8; j++) {
            int k = kb * 32 + kkb * 8 + j;
            float val = (n < D_HID) ? W1[n * D_MODEL + k] : 0.f;
            o[j] = f2bf(val);
        }
        int off = kb * 8192 + n * 64 + ((kkb ^ ((n >> 1) & 3)) * 16);
        *(short8*)(ws + WS_W1P + off) = o;
    } else if (id < 86016 + 2048) {   // W2p: 4 kb * 128 n * 4 kkb
        int id2 = id - 86016;
        int kb = id2 >> 9;
        int rem = id2 & 511;
        int n = rem >> 2, kkb = rem & 3;
        short8 o;
        #pragma unroll
        for (int j = 0; j < 8; j++) {
            int k = kb * 32 + kkb * 8 + j;
            float val = (n < D_HID && k < D_HID) ? W2[n * D_HID + k] : 0.f;
            o[j] = f2bf(val);
        }
        int off = kb * 8192 + n * 64 + ((kkb ^ ((n >> 1) & 3)) * 16);
        *(short8*)(ws + WS_W2P + off) = o;
    } else if (id < 86016 + 2048 + 512) {  // qvp: 4 kb * 32 n * 4 kkb
        int id3 = id - 86016 - 2048;
        int kb = id3 >> 7;
        int rem = id3 & 127;
        int n = rem >> 2, kkb = rem & 3;
        short8 o;
        #pragma unroll
        for (int j = 0; j < 8; j++) {
            int k = kb * 32 + kkb * 8 + j;
            float val = 0.f;
            if (k < D_HID) {
                if (n < NH)            val = q[n * D_HID + k];
                else if (n < 2 * NH)   val = v[(n - NH) * D_HID + k];
            }
            o[j] = f2bf(val);
        }
        int off = kb * 2048 + n * 64 + ((kkb ^ ((n >> 1) & 3)) * 16);
        *(short8*)(ws + WS_QVP + off) = o;
    } else {                               // biases, padded to 128
        int id4 = id - 86016 - 2048 - 512;
        if (id4 < 128) {
            ((float*)(ws + WS_B1P))[id4] = (id4 < D_HID) ? b1[id4] : 0.f;
        } else if (id4 < 256) {
            int i = id4 - 128;
            ((float*)(ws + WS_B2P))[i] = (i < D_HID) ? b2[i] : 0.f;
        }
    }
}

// ---------------- fused MLP: x -> h1 -> y -> attn/vals ----------------------
__global__ __launch_bounds__(256, 2) void mlp_kernel(
    const float* __restrict__ x, const char* __restrict__ W1p,
    const char* __restrict__ W2p, const char* __restrict__ qvp,
    const float* __restrict__ b1p, const float* __restrict__ b2p,
    float* __restrict__ av) {
    // LDS: [0,16384) = W1 tile double-buffer during K-loop;
    //      [0,17408) = y1 (64 x 136 bf16), [17408,34816) = y2 (after K-loop)
    __shared__ __align__(16) char smem[34816];
    short* y1 = (short*)smem;
    short* y2 = (short*)(smem + 17408);

    const int tid = threadIdx.x;
    const int w = tid >> 6, lane = tid & 63;
    const int lr = lane & 15, lq = lane >> 4;
    const int blk = blockIdx.x;
    const int rowbase = blk * BM + w * 16;
    const int swz = (lq ^ ((lr >> 1) & 3)) * 16;

    // A-fragment source: x row (rowbase+lr), k chunk lq*8
    const float* xA = x + (size_t)(rowbase + lr) * D_MODEL + lq * 8;
    // B staging source: contiguous packed tile, thread covers 32B
    const char* gB = W1p + tid * 32;

    f32x4 acc[8];
    #pragma unroll
    for (int i = 0; i < 8; i++) acc[i] = (f32x4)0.f;

    // prologue loads for iter 0
    float4 a0 = *(const float4*)(xA);
    float4 a1 = *(const float4*)(xA + 4);
    uint4  s0 = *(const uint4*)(gB);
    uint4  s1 = *(const uint4*)(gB + 16);

    #pragma unroll 2
    for (int i = 0; i < KITERS; i++) {
        char* bb = smem + (i & 1) * 8192;
        // consume B staging regs -> LDS (waits vmcnt as needed)
        *(uint4*)(bb + tid * 32)      = s0;
        *(uint4*)(bb + tid * 32 + 16) = s1;
        // consume A regs -> bf16 fragment
        short8 afrag;
        afrag[0] = f2bf(a0.x); afrag[1] = f2bf(a0.y);
        afrag[2] = f2bf(a0.z); afrag[3] = f2bf(a0.w);
        afrag[4] = f2bf(a1.x); afrag[5] = f2bf(a1.y);
        afrag[6] = f2bf(a1.z); afrag[7] = f2bf(a1.w);
        __syncthreads();
        // prefetch i+1 AFTER the barrier so loads overlap compute
        if (i + 1 < KITERS) {
            xA += 32; gB += 8192;
            a0 = *(const float4*)(xA);
            a1 = *(const float4*)(xA + 4);
            s0 = *(const uint4*)(gB);
            s1 = *(const uint4*)(gB + 16);
        }
        const char* bbr = smem + (i & 1) * 8192;
        const int baddr = lr * 64 + swz;
        #pragma unroll
        for (int nt = 0; nt < 8; nt++) {
            short8 bfrag = *(const short8*)(bbr + baddr + nt * 1024);
            acc[nt] = __builtin_amdgcn_mfma_f32_16x16x32_bf16(afrag, bfrag, acc[nt], 0, 0, 0);
        }
    }
    __syncthreads();   // all waves done reading Bbuf; smem now reused as y1

    // epilogue 1: bias + relu -> y1 (bf16, stride 136)
    #pragma unroll
    for (int nt = 0; nt < 8; nt++) {
        float bias = b1p[nt * 16 + lr];
        #pragma unroll
        for (int r = 0; r < 4; r++) {
            float vv = acc[nt][r] + bias;
            vv = vv > 0.f ? vv : 0.f;
            y1[(w * 16 + lq * 4 + r) * 136 + nt * 16 + lr] = f2bf(vv);
        }
    }
    __syncthreads();

    // stage 2: h2 = relu(y1 @ W2p^T + b2)
    f32x4 acc2[8];
    #pragma unroll
    for (int i = 0; i < 8; i++) acc2[i] = (f32x4)0.f;
    #pragma unroll
    for (int kt = 0; kt < 4; kt++) {
        short8 a2 = *(const short8*)(y1 + (w * 16 + lr) * 136 + kt * 32 + lq * 8);
        #pragma unroll
        for (int nt = 0; nt < 8; nt++) {
            short8 b2f = *(const short8*)(W2p + kt * 8192 + (nt * 16 + lr) * 64 + swz);
            acc2[nt] = __builtin_amdgcn_mfma_f32_16x16x32_bf16(a2, b2f, acc2[nt], 0, 0, 0);
        }
    }
    #pragma unroll
    for (int nt = 0; nt < 8; nt++) {
        float bias = b2p[nt * 16 + lr];
        #pragma unroll
        for (int r = 0; r < 4; r++) {
            float vv = acc2[nt][r] + bias;
            vv = vv > 0.f ? vv : 0.f;
            y2[(w * 16 + lq * 4 + r) * 136 + nt * 16 + lr] = f2bf(vv);
        }
    }
    __syncthreads();

    // stage 3: attn/vals = y2 @ qv^T  (cols 0..9 attn, 10..19 vals)
    f32x4 acc3[2];
    acc3[0] = (f32x4)0.f; acc3[1] = (f32x4)0.f;
    #pragma unroll
    for (int kt = 0; kt < 4; kt++) {
        short8 a3 = *(const short8*)(y2 + (w * 16 + lr) * 136 + kt * 32 + lq * 8);
        #pragma unroll
        for (int nt = 0; nt < 2; nt++) {
            short8 b3f = *(const short8*)(qvp + kt * 2048 + (nt * 16 + lr) * 64 + swz);
            acc3[nt] = __builtin_amdgcn_mfma_f32_16x16x32_bf16(a3, b3f, acc3[nt], 0, 0, 0);
        }
    }
    #pragma unroll
    for (int nt = 0; nt < 2; nt++) {
        #pragma unroll
        for (int r = 0; r < 4; r++) {
            av[(size_t)(rowbase + lq * 4 + r) * 32 + nt * 16 + lr] = acc3[nt][r];
        }
    }
}

// ---------------- rolling window softmax pool + max over time ---------------
__global__ void roll_kernel(const float* __restrict__ av, const void* __restrict__ maskp,
                            float* __restrict__ hmax) {
    const int blk = blockIdx.x;
    const int b = blk / NH, h = blk % NH;
    const unsigned char* mb = (const unsigned char*)maskp;
    const int* mi = (const int*)maskp;
    // lengths >= 1024 so mask[0][1] is true: byte layout iff byte[1] != 0
    const bool bytelay = (mb[1] != 0);
    const int tid = threadIdx.x;
    const float* avb = av + (size_t)b * TLEN * 32;
    float lmax = -INFINITY;
    for (int t = tid; t < TLEN; t += 256) {
        bool mt = bytelay ? (mb[b * TLEN + t] != 0) : (mi[b * TLEN + t] != 0);
        if (!mt) continue;
        float wa[WIN], wv[WIN];
        float m = -INFINITY;
        #pragma unroll
        for (int j = 0; j < WIN; j++) {
            int s = t - (WIN - 1) + j;
            bool valid = (s >= 0) &&
                         (bytelay ? (mb[b * TLEN + s] != 0) : (mi[b * TLEN + s] != 0));
            if (valid) { wa[j] = avb[s * 32 + h]; wv[j] = avb[s * 32 + 10 + h]; }
            else       { wa[j] = -INFINITY;       wv[j] = 0.f; }
            m = fmaxf(m, wa[j]);
        }
        float den = 0.f, num = 0.f;
        #pragma unroll
        for (int j = 0; j < WIN; j++) {
            float e = __expf(wa[j] - m);   // exp(-inf) = 0 kills invalid slots
            den += e;
            num += e * wv[j];
        }
        lmax = fmaxf(lmax, num / den);
    }
    #pragma unroll
    for (int off = 32; off >= 1; off >>= 1)
        lmax = fmaxf(lmax, __shfl_down(lmax, off));
    __shared__ float red[4];
    if ((tid & 63) == 0) red[tid >> 6] = lmax;
    __syncthreads();
    if (tid == 0) {
        hmax[blk] = fmaxf(fmaxf(red[0], red[1]), fmaxf(red[2], red[3]));
    }
}

// ---------------- final: sum heads + bias -----------------------------------
__global__ void final_kernel(const float* __restrict__ hmax, const float* __restrict__ bias,
                             float* __restrict__ out) {
    int tid = threadIdx.x;
    if (tid < BATCH) {
        float s = bias[0];
        #pragma unroll
        for (int h = 0; h < NH; h++) s += hmax[tid * NH + h];
        out[tid] = s;
    }
}

extern "C" void kernel_launch(void* const* d_in, const int* in_sizes, int n_in,
                              void* d_out, int out_size, void* d_ws, size_t ws_size,
                              hipStream_t stream) {
    const float* x    = (const float*)d_in[0];
    const void*  mask = d_in[1];
    const float* W1   = (const float*)d_in[2];
    const float* b1   = (const float*)d_in[3];
    const float* W2   = (const float*)d_in[4];
    const float* b2   = (const float*)d_in[5];
    const float* q    = (const float*)d_in[6];
    const float* v    = (const float*)d_in[7];
    const float* bias = (const float*)d_in[8];
    char* ws = (char*)d_ws;

    const char*  W1p  = ws + WS_W1P;
    const char*  W2p  = ws + WS_W2P;
    const char*  qvp  = ws + WS_QVP;
    const float* b1p  = (const float*)(ws + WS_B1P);
    const float* b2p  = (const float*)(ws + WS_B2P);
    float*       av   = (float*)(ws + WS_AV);
    float*       hmax = (float*)(ws + WS_HMAX);

    prep_kernel<<<dim3(347), dim3(256), 0, stream>>>(W1, b1, W2, b2, q, v, ws);
    mlp_kernel<<<dim3(M_TOT / BM), dim3(256), 0, stream>>>(x, W1p, W2p, qvp, b1p, b2p, av);
    roll_kernel<<<dim3(BATCH * NH), dim3(256), 0, stream>>>(av, mask, hmax);
    final_kernel<<<dim3(1), dim3(64), 0, stream>>>(hmax, bias, (float*)d_out);
}